// Round 12
// baseline (124.076 us; speedup 1.0000x reference)
//
#include <hip/hip_runtime.h>
#include <cstdint>
#include <cstddef>

typedef __attribute__((ext_vector_type(8))) __bf16 bf16x8;
typedef __attribute__((ext_vector_type(4))) float f32x4;

#define LOG2E 1.44269504088896340736f
#define SCL (0.125f * LOG2E)   // fold 1/sqrt(64) into exp2 scale

constexpr int N_ = 8;
constexpr int S_ = 2048;
constexpr int D_ = 64;
constexpr int V_ = 64;
constexpr int TQ = 16;   // queries per block
constexpr int CK = 64;   // keys per loop iteration (two 32-key MFMA sub-chunks)
constexpr int NW = 4;    // waves per block (K-split)

__device__ __forceinline__ ushort f2bf(float x) {      // fp32 -> bf16 RNE
    uint u = __builtin_bit_cast(uint, x);
    return (ushort)((u + 0x7FFFu + ((u >> 16) & 1u)) >> 16);
}
__device__ __forceinline__ bf16x8 ld8(const ushort* p) {
    uint4 u = *reinterpret_cast<const uint4*>(p);
    return __builtin_bit_cast(bf16x8, u);
}

// prefix_len dtype sniff (int64 iff hi-words all zero; values < 2048).
__device__ __forceinline__ int load_prefix(const int* plen, int n) {
    bool is64 = ((plen[1] | plen[3] | plen[5] | plen[7]) == 0);
    return is64 ? plen[2 * n] : plen[n];
}

// fp32 Q/K/V -> bf16 Qb/Kb + bf16 VT[n][v][s].  1024 blocks (4/CU) of 256
// threads, 4 elems/thread: R9-11's 256-block version was latency-bound at
// ~40us (gap accounting vs R7's single-kernel 18us overhead).
__global__ __launch_bounds__(256) void prep_kernel(
    const float* __restrict__ Q, const float* __restrict__ K,
    const float* __restrict__ V, ushort* __restrict__ Qb,
    ushort* __restrict__ Kb, ushort* __restrict__ VTb)
{
    __shared__ ushort Vl[16][65];        // 16 keys x 64 dims, padded
    const int b  = blockIdx.x;           // 1024 blocks: n = b>>7, s-tile = b&127
    const int t  = threadIdx.x;
    const int n  = b >> 7;
    const int s0 = (b & 127) << 4;       // 16 rows per block
    const size_t base = (size_t)b * 1024;   // == (n*S_+s0)*64

    const int i4 = t * 4;
    f32x4 qv = *reinterpret_cast<const f32x4*>(Q + base + i4);
    f32x4 kv = *reinterpret_cast<const f32x4*>(K + base + i4);
    f32x4 vv = *reinterpret_cast<const f32x4*>(V + base + i4);
    ushort4 qo, ko;
    qo.x = f2bf(qv[0]); qo.y = f2bf(qv[1]); qo.z = f2bf(qv[2]); qo.w = f2bf(qv[3]);
    ko.x = f2bf(kv[0]); ko.y = f2bf(kv[1]); ko.z = f2bf(kv[2]); ko.w = f2bf(kv[3]);
    *reinterpret_cast<ushort4*>(Qb + base + i4) = qo;
    *reinterpret_cast<ushort4*>(Kb + base + i4) = ko;

    const int row = t >> 4;              // 0..15 (key within tile)
    const int col = (t & 15) * 4;        // dim
    Vl[row][col + 0] = f2bf(vv[0]);
    Vl[row][col + 1] = f2bf(vv[1]);
    Vl[row][col + 2] = f2bf(vv[2]);
    Vl[row][col + 3] = f2bf(vv[3]);
    __syncthreads();

    // VT write: thread -> (v-dim d = t>>2, 4-key chunk)
    const int d  = t >> 2;
    const int k0 = (t & 3) * 4;
    ushort4 o;
    o.x = Vl[k0 + 0][d];
    o.y = Vl[k0 + 1][d];
    o.z = Vl[k0 + 2][d];
    o.w = Vl[k0 + 3][d];
    *reinterpret_cast<ushort4*>(VTb + ((size_t)(n * V_ + d)) * S_ + s0 + k0) = o;
}

// Transposed-score flash attention (R11 scheme, verified):
//  S^T = K_perm . Q^T (A=K-frag rows permuted, B=Q-frag), exp'd scores land
//  directly in the B-fragment layout of P^T; O^T = V^T . P^T with VT rows.
//  Zero LDS in the K-loop. CK=64: two independent 32-key sub-chunks per
//  iteration -> 16 loads in flight, 2x ILP, half the trip count.
__global__ __launch_bounds__(256, 4) void attn_kernel(
    const ushort* __restrict__ Qb, const ushort* __restrict__ Kb,
    const ushort* __restrict__ VTb, const int* __restrict__ plen,
    float* __restrict__ outm)
{
    __shared__ float obuf[NW][TQ][V_ + 4];
    __shared__ float lbuf[NW][TQ];

    const int bx   = blockIdx.x;      // 1024 blocks, batch-interleaved
    const int n    = bx & 7;
    const int q0   = (bx >> 3) * TQ;
    const int tid  = threadIdx.x;
    const int w    = tid >> 6;        // wave 0..3
    const int lane = tid & 63;
    const int quad = lane >> 4;
    const int l16  = lane & 15;
    const int prefix = load_prefix(plen, n);

    const ushort* qptr = Qb + ((size_t)(n * S_ + q0 + l16)) * D_ + quad * 8;
    const bf16x8 qf0 = ld8(qptr);
    const bf16x8 qf1 = ld8(qptr + 32);

    f32x4 oacc[4];
#pragma unroll
    for (int vb = 0; vb < 4; vb++) oacc[vb] = (f32x4){0.f, 0.f, 0.f, 0.f};
    float l_acc = 0.f;

    const int nPC = (prefix + CK - 1) / CK;      // 64-key chunks over prefix
    const int dc  = q0 / CK;                     // diag chunk (tile fits in one)
    const bool hasDiag = (dc >= nPC) && ((dc & (NW - 1)) == w);
    const int rp = 8 * (l16 >> 2) + (l16 & 3);   // permuted K-row offset
    const int qrow = q0 + l16;

    auto process = [&](int kb) {
        // A-operand K fragments for both 32-key halves (8 x 16B loads)
        const ushort* kp0 = Kb + ((size_t)(n * S_ + kb + rp)) * D_ + quad * 8;
        const ushort* kp2 = kp0 + 32 * D_;
        bf16x8 ka0 = ld8(kp0);           bf16x8 ka1 = ld8(kp0 + 32);
        bf16x8 kb0 = ld8(kp0 + 4 * D_);  bf16x8 kb1 = ld8(kp0 + 4 * D_ + 32);
        bf16x8 kc0 = ld8(kp2);           bf16x8 kc1 = ld8(kp2 + 32);
        bf16x8 kd0 = ld8(kp2 + 4 * D_);  bf16x8 kd1 = ld8(kp2 + 4 * D_ + 32);

        const f32x4 zero = (f32x4){0.f, 0.f, 0.f, 0.f};
        f32x4 s0 = __builtin_amdgcn_mfma_f32_16x16x32_bf16(ka0, qf0, zero, 0, 0, 0);
        s0 = __builtin_amdgcn_mfma_f32_16x16x32_bf16(ka1, qf1, s0, 0, 0, 0);
        f32x4 s1 = __builtin_amdgcn_mfma_f32_16x16x32_bf16(kb0, qf0, zero, 0, 0, 0);
        s1 = __builtin_amdgcn_mfma_f32_16x16x32_bf16(kb1, qf1, s1, 0, 0, 0);
        f32x4 s2 = __builtin_amdgcn_mfma_f32_16x16x32_bf16(kc0, qf0, zero, 0, 0, 0);
        s2 = __builtin_amdgcn_mfma_f32_16x16x32_bf16(kc1, qf1, s2, 0, 0, 0);
        f32x4 s3 = __builtin_amdgcn_mfma_f32_16x16x32_bf16(kd0, qf0, zero, 0, 0, 0);
        s3 = __builtin_amdgcn_mfma_f32_16x16x32_bf16(kd1, qf1, s3, 0, 0, 0);
        // S^T: lane holds S[key = kb + off + 8*quad + 4t + r][q0+l16]
        //   s0/s1: off=0, t=0/1;  s2/s3: off=32, t=0/1

        bf16x8 pf0, pf1;   // B-fragments of P^T for the two halves
#pragma unroll
        for (int t = 0; t < 2; t++) {
#pragma unroll
            for (int r = 0; r < 4; r++) {
                int k0 = kb + 8 * quad + 4 * t + r;
                int k1 = k0 + 32;
                float x0 = (t ? s1[r] : s0[r]) * SCL;
                float x1 = (t ? s3[r] : s2[r]) * SCL;
                bool ok0 = (k0 < prefix) || (k0 == qrow);
                bool ok1 = (k1 < prefix) || (k1 == qrow);
                float p0 = ok0 ? exp2f(x0) : 0.f;
                float p1 = ok1 ? exp2f(x1) : 0.f;
                l_acc += p0 + p1;
                pf0[t * 4 + r] = __builtin_bit_cast(__bf16, f2bf(p0));
                pf1[t * 4 + r] = __builtin_bit_cast(__bf16, f2bf(p1));
            }
        }
        // PV: O^T += V^T . P^T for both halves
#pragma unroll
        for (int vb = 0; vb < 4; vb++) {
            const ushort* vp = VTb + ((size_t)(n * V_ + vb * 16 + l16)) * S_ + kb + quad * 8;
            bf16x8 vf0 = ld8(vp);
            bf16x8 vf1 = ld8(vp + 32);
            oacc[vb] = __builtin_amdgcn_mfma_f32_16x16x32_bf16(vf0, pf0, oacc[vb], 0, 0, 0);
            oacc[vb] = __builtin_amdgcn_mfma_f32_16x16x32_bf16(vf1, pf1, oacc[vb], 0, 0, 0);
        }
    };

    for (int c = w; c < nPC; c += NW) process(c * CK);
    if (hasDiag) process(dc * CK);

    // one-time l reduction across quads (lanes sharing l16)
    l_acc += __shfl_xor(l_acc, 16, 64);
    l_acc += __shfl_xor(l_acc, 32, 64);
    if (quad == 0) lbuf[w][l16] = l_acc;
    // O^T C-layout: lane holds O[q = l16][v = vb*16 + quad*4 + r]
#pragma unroll
    for (int vb = 0; vb < 4; vb++) {
#pragma unroll
        for (int r = 0; r < 4; r++)
            obuf[w][l16][vb * 16 + quad * 4 + r] = oacc[vb][r];
    }
    __syncthreads();

    // merge 4 K-split partials (plain sums)
    const int row = tid >> 4;
    const int vd0 = (tid & 15) * 4;
    float lg = 0.f;
    float acc[4] = {0.f, 0.f, 0.f, 0.f};
#pragma unroll
    for (int ww = 0; ww < NW; ww++) {
        lg += lbuf[ww][row];
#pragma unroll
        for (int i = 0; i < 4; i++) acc[i] += obuf[ww][row][vd0 + i];
    }
    float inv = 1.f / lg;   // lg > 0: diagonal key never masked
    f32x4 o4 = (f32x4){acc[0] * inv, acc[1] * inv, acc[2] * inv, acc[3] * inv};
    *reinterpret_cast<f32x4*>(outm + ((size_t)(n * S_ + q0 + row)) * V_ + vd0) = o4;
}

extern "C" void kernel_launch(void* const* d_in, const int* in_sizes, int n_in,
                              void* d_out, int out_size, void* d_ws, size_t ws_size,
                              hipStream_t stream) {
    // World C (verified R7/R8): fp32 Q/K/V, int32 prefix_len (sniffed), fp32 out.
    const float* Qf = (const float*)d_in[0];
    const float* Kf = (const float*)d_in[1];
    const float* Vf = (const float*)d_in[2];
    const int* plen = (const int*)d_in[3];
    float* outm = (float*)d_out;

    constexpr size_t ELEMS = (size_t)N_ * S_ * D_;   // 2^20
    ushort* Qb  = (ushort*)d_ws;                     // 6 MB total
    ushort* Kb  = Qb + ELEMS;
    ushort* VTb = Kb + ELEMS;

    prep_kernel<<<1024, 256, 0, stream>>>(Qf, Kf, Vf, Qb, Kb, VTb);
    attn_kernel<<<(S_ / TQ) * N_, 256, 0, stream>>>(Qb, Kb, VTb, plen, outm);
}